// Round 12
// baseline (84.715 us; speedup 1.0000x reference)
//
#include <hip/hip_runtime.h>
#include <hip/hip_bf16.h>

#define FEPS 1e-5f

constexpr int Bn = 4, Hn = 16, Sn = 4096, Dn = 64;
constexpr int NHEAD = Bn * Hn;          // 64 heads
constexpr int SLOT = Dn * Dn + Dn;      // final fp32 slot: 4096 kv + 64 ksum
constexpr int SLOTB = Dn * Dn / 2 + Dn; // bf16 partial: 2048 u32 kv + 64 f32 ksum

typedef short short8 __attribute__((ext_vector_type(8)));
typedef float f32x4 __attribute__((ext_vector_type(4)));

__device__ __forceinline__ unsigned short f2bfu(float f) {
    __hip_bfloat16 h = __float2bfloat16(f);
    return __builtin_bit_cast(unsigned short, h);
}
__device__ __forceinline__ unsigned pack2(float a, float b) {
    return (unsigned)f2bfu(a) | ((unsigned)f2bfu(b) << 16);
}
__device__ __forceinline__ float elem4(const float4& v, int i) {
    return i == 0 ? v.x : i == 1 ? v.y : i == 2 ? v.z : v.w;
}

// ---------------- Pass 1 (MFMA, one 32-row slice per wave) ----------------
// chunks=32 -> ch_s=128 -> each wave does EXACTLY ONE slice: issue 16
// coalesced dwordx4 loads (16KB in flight), progressive vmcnt drain into CVT,
// 16 MFMA, epilogue. No main loop => compiler cannot serialize/sink loads.
// 2048 blocks (8/CU supply), peak liveness ~110 VGPR -> 4-5 waves/SIMD.
// Column-permuted fragments (R10, proven): tile mt owns d-columns {4c+mt};
// A/B share the (lane,j)->s map so k-pairing is layout-invariant.
// Partials written bf16-packed (halves partial traffic); ksum stays fp32.
__global__ __launch_bounds__(256, 3) void pass1(const float* __restrict__ K,
                                                const float* __restrict__ V,
                                                unsigned* __restrict__ partb,
                                                int ch_s) {
    __shared__ float red[2048];   // 64 x 32 e-half reduction buffer
    __shared__ float ksr[256];    // per-wave ksum partials

    const int head = blockIdx.x;
    const int chunk = blockIdx.y;
    const int t = threadIdx.x;
    const int w = t >> 6;                  // wave 0..3
    const int l = t & 63;
    const int q16 = l >> 4;                // lane group 0..3
    const int lc = l & 15;                 // lane col 0..15
    const int wave_s = ch_s >> 2;          // s-rows per wave
    const int nsl = wave_s >> 5;           // 32-row slices per wave (1 at chunks=32)

    const size_t hbase = (size_t)head * Sn * Dn;
    const size_t s0w = (size_t)chunk * ch_s + (size_t)w * wave_s;
    const float4* Kp4 = (const float4*)(K + hbase + (s0w + q16 * 8) * Dn) + lc;
    const float4* Vp4 = (const float4*)(V + hbase + (s0w + q16 * 8) * Dn) + lc;

    f32x4 acc[4][4] = {};                  // [mt][nt]; true d=4*m_loc+mt, e=4*n_loc+nt
    float ks[4] = {0.f, 0.f, 0.f, 0.f};    // fp32 ksum partial for col 4*lc+mt

    for (int sl = 0; sl < nsl; ++sl) {
        float4 kr[8], vr[8];
        #pragma unroll
        for (int j = 0; j < 8; ++j) {
            kr[j] = Kp4[(sl * 32 + j) * 16];
            vr[j] = Vp4[(sl * 32 + j) * 16];
        }
        short8 af[4], bfr[4];
        #pragma unroll
        for (int mt = 0; mt < 4; ++mt) {
            short8 a, b;
            #pragma unroll
            for (int j = 0; j < 8; ++j) {
                float kf = elem4(kr[j], mt);
                float vf = elem4(vr[j], mt);
                a[j] = (short)f2bfu(kf);
                ks[mt] += kf;
                b[j] = (short)f2bfu(vf);
            }
            af[mt] = a;
            bfr[mt] = b;
        }
        #pragma unroll
        for (int mt = 0; mt < 4; ++mt)
            #pragma unroll
            for (int nt = 0; nt < 4; ++nt)
                acc[mt][nt] = __builtin_amdgcn_mfma_f32_16x16x32_bf16(
                    af[mt], bfr[nt], acc[mt][nt], 0, 0, 0);
    }

    // ksum: reduce across the 4 q16 lane groups
    #pragma unroll
    for (int mt = 0; mt < 4; ++mt) {
        ks[mt] += __shfl_xor(ks[mt], 16);
        ks[mt] += __shfl_xor(ks[mt], 32);
    }
    if (l < 16) {                          // lane l holds column 4*l+mt
        #pragma unroll
        for (int mt = 0; mt < 4; ++mt) ksr[w * Dn + 4 * l + mt] = ks[mt];
    }

    // ---- epilogue: reduce 4 wave partials in two 64x32 e-halves, pack bf16 ----
    unsigned* slot = partb + ((size_t)chunk * NHEAD + head) * SLOTB;
    const int ehalf = lc >> 3;             // e = 4*lc+nt -> half = lc>>3
    const int ebase = 4 * (lc & 7);        // e offset within half (+nt)
    #pragma unroll
    for (int h = 0; h < 2; ++h) {
        #pragma unroll
        for (int ww = 0; ww < 4; ++ww) {
            __syncthreads();
            if (w == ww && ehalf == h) {
                #pragma unroll
                for (int mt = 0; mt < 4; ++mt)
                    #pragma unroll
                    for (int nt = 0; nt < 4; ++nt)
                        #pragma unroll
                        for (int r = 0; r < 4; ++r) {
                            int d = 16 * q16 + 4 * r + mt;   // 4*m_loc+mt
                            int eo = ebase + nt;
                            float v = acc[mt][nt][r];
                            if (ww == 0) red[d * 32 + eo] = v;
                            else         red[d * 32 + eo] += v;
                        }
            }
        }
        __syncthreads();
        // pack + write this e-half: red[d*32+eo] -> slotb word (d*64+h*32+eo)/2
        #pragma unroll
        for (int q = 0; q < 2; ++q) {
            int f = q * 1024 + t * 4;      // 0..2047, multiple of 4
            int d = f >> 5, eo = f & 31;
            const float4 v = *(const float4*)&red[f];
            uint2 p;
            p.x = pack2(v.x, v.y);
            p.y = pack2(v.z, v.w);
            *(uint2*)&slot[d * 32 + h * 16 + (eo >> 1)] = p;
        }
    }
    if (t < Dn) {
        float s = ksr[t] + ksr[Dn + t] + ksr[2 * Dn + t] + ksr[3 * Dn + t];
        slot[Dn * Dn / 2 + t] = __builtin_bit_cast(unsigned, s);
    }
}

// ---------------- Reduce bf16 chunk-partials -> final fp32 slots ----------------
__global__ __launch_bounds__(256) void reduce_partials(const unsigned* __restrict__ partb,
                                                       float* __restrict__ slots,
                                                       int nchunks) {
    const int head = blockIdx.x;
    const int idx = blockIdx.y * 256 + threadIdx.x;
    if (idx >= SLOTB) return;
    if (idx < Dn * Dn / 2) {
        float lo = 0.f, hi = 0.f;
        for (int c = 0; c < nchunks; ++c) {
            unsigned u = partb[((size_t)c * NHEAD + head) * SLOTB + idx];
            lo += __builtin_bit_cast(float, u << 16);
            hi += __builtin_bit_cast(float, u & 0xffff0000u);
        }
        // word idx <-> kv index: d = idx>>5, h = (idx>>4)&1, e2 = idx&15
        int kvi = (idx >> 5) * Dn + ((idx >> 4) & 1) * 32 + (idx & 15) * 2;
        float* dst = slots + (size_t)head * SLOT + kvi;
        dst[0] = lo;
        dst[1] = hi;
    } else {
        float s = 0.f;
        for (int c = 0; c < nchunks; ++c)
            s += __builtin_bit_cast(float,
                partb[((size_t)c * NHEAD + head) * SLOTB + idx]);
        slots[(size_t)head * SLOT + Dn * Dn + (idx - Dn * Dn / 2)] = s;
    }
}

// ---------------- Pass 2: out = (Q / (Q.ksum + eps)) @ kv ----------------
__global__ __launch_bounds__(256) void pass2(const float* __restrict__ Q,
                                             const float* __restrict__ slots,
                                             float* __restrict__ out) {
    const int head = blockIdx.x;
    const int rc = blockIdx.y;  // 64-row chunk
    const int t = threadIdx.x;
    const int ti = t >> 4, tj = t & 15;
    const int r0 = ti * 4, e0 = tj * 4;   // 4 rows x 4 cols per thread

    __shared__ float kvs[Dn][Dn];
    __shared__ float qT[Dn][68];          // transposed Q tile, padded
    __shared__ float kss[Dn];

    const float* kvh = slots + (size_t)head * SLOT;

    const float4* kvsrc = (const float4*)kvh;
    float4* kvdst = (float4*)&kvs[0][0];
    #pragma unroll
    for (int kk = 0; kk < 4; ++kk) kvdst[t + 256 * kk] = kvsrc[t + 256 * kk];
    if (t < 16) ((float4*)kss)[t] = ((const float4*)(kvh + Dn * Dn))[t];

    const float4* Qsrc = (const float4*)(Q + ((size_t)head * Sn + (size_t)rc * 64) * Dn);
    #pragma unroll
    for (int kk = 0; kk < 4; ++kk) {
        int f = t + 256 * kk;
        int row = f >> 4, d4 = (f & 15) * 4;
        float4 q4 = Qsrc[f];
        qT[d4 + 0][row] = q4.x;
        qT[d4 + 1][row] = q4.y;
        qT[d4 + 2][row] = q4.z;
        qT[d4 + 3][row] = q4.w;
    }
    __syncthreads();

    float acc[4][4] = {};
    float dn[4] = {0.f, 0.f, 0.f, 0.f};
    #pragma unroll 8
    for (int d = 0; d < Dn; ++d) {
        float4 a = *(const float4*)&qT[d][r0];
        float4 b = *(const float4*)&kvs[d][e0];
        float ksd = kss[d];
        float av[4] = {a.x, a.y, a.z, a.w};
        float bv[4] = {b.x, b.y, b.z, b.w};
        #pragma unroll
        for (int i = 0; i < 4; ++i) {
            dn[i] += av[i] * ksd;
            #pragma unroll
            for (int j = 0; j < 4; ++j) acc[i][j] += av[i] * bv[j];
        }
    }

    float* Oh = out + ((size_t)head * Sn + (size_t)rc * 64) * Dn;
    #pragma unroll
    for (int i = 0; i < 4; ++i) {
        float inv = 1.0f / (dn[i] + FEPS);
        float4 r;
        r.x = acc[i][0] * inv; r.y = acc[i][1] * inv;
        r.z = acc[i][2] * inv; r.w = acc[i][3] * inv;
        *(float4*)&Oh[(size_t)(r0 + i) * Dn + e0] = r;
    }
}

extern "C" void kernel_launch(void* const* d_in, const int* in_sizes, int n_in,
                              void* d_out, int out_size, void* d_ws, size_t ws_size,
                              hipStream_t stream) {
    (void)in_sizes; (void)n_in; (void)out_size;
    const float* Q = (const float*)d_in[0];
    const float* K = (const float*)d_in[1];
    const float* V = (const float*)d_in[2];
    float* out = (float*)d_out;

    float* slots = (float*)d_ws;                               // [64][4160] fp32
    unsigned* partb = (unsigned*)(slots + (size_t)NHEAD * SLOT); // [chunks][64][2112]

    // largest chunk count whose bf16 partial buffer fits (32 preferred: nsl=1)
    int chunks = 1;
    const int cand[6] = {32, 16, 8, 4, 2, 1};
    for (int ci = 0; ci < 6; ++ci) {
        size_t need = (size_t)NHEAD * SLOT * 4 + (size_t)cand[ci] * NHEAD * SLOTB * 4;
        if (need <= ws_size) { chunks = cand[ci]; break; }
    }

    hipLaunchKernelGGL(pass1, dim3(NHEAD, chunks), dim3(256), 0, stream,
                       K, V, partb, Sn / chunks);
    hipLaunchKernelGGL(reduce_partials, dim3(NHEAD, (SLOTB + 255) / 256), dim3(256), 0, stream,
                       partb, slots, chunks);
    hipLaunchKernelGGL(pass2, dim3(NHEAD, Sn / 64), dim3(256), 0, stream,
                       Q, slots, out);
}